// Round 1
// baseline (327.815 us; speedup 1.0000x reference)
//
#include <hip/hip_runtime.h>
#include <hip/hip_bf16.h>

typedef __bf16 bf16x8 __attribute__((ext_vector_type(8)));
typedef float f32x4 __attribute__((ext_vector_type(4)));
typedef short s16x8 __attribute__((ext_vector_type(8)));
typedef short s16x4 __attribute__((ext_vector_type(4)));

#define NTOK 49
#define CDIM 96
#define XS_S 104   // bf16 row stride for Xs/Vs/Qs/Ks/OUTs (208B = 13*16, conflict-light)
#define SS_S 68    // f32 row stride for scores (272B = 17*16)
#define VT_S 72    // bf16 row stride for VVT (144B = 9*16)
#define PS_S 72    // bf16 row stride for P

__device__ __forceinline__ unsigned short f2bf(float f) {
  __hip_bfloat16 h = __float2bfloat16(f);
  return __builtin_bit_cast(unsigned short, h);
}

// d_ws layout:
//   ushort[0      .. 9216 )  wqT   [oc 96][ic 96]   (bf16 bits)
//   ushort[9216   .. 27648)  wkvT  [oc 192][ic 96]
//   ushort[27648  .. 36864)  wprojT[oc 96][ic 96]
//   byte 73728: float biasf[3][49][64]  (rpb gathered, cols 49..63 = 0)
__global__ void prep(const float* __restrict__ wq, const float* __restrict__ wkv,
                     const float* __restrict__ wproj, const float* __restrict__ rpb,
                     const int* __restrict__ relidx, unsigned short* __restrict__ wsT,
                     float* __restrict__ biasf) {
  const int total = 36864 + 3 * 49 * 64;
  for (int i = blockIdx.x * 256 + threadIdx.x; i < total; i += gridDim.x * 256) {
    if (i < 9216) {
      int oc = i / 96, ic = i - oc * 96;
      wsT[i] = f2bf(wq[ic * 96 + oc]);
    } else if (i < 27648) {
      int j = i - 9216; int oc = j / 96, ic = j - oc * 96;
      wsT[i] = f2bf(wkv[ic * 192 + oc]);
    } else if (i < 36864) {
      int j = i - 27648; int oc = j / 96, ic = j - oc * 96;
      wsT[i] = f2bf(wproj[ic * 96 + oc]);
    } else {
      int j = i - 36864; int h = j / 3136; int rc = j - h * 3136;
      int r = rc >> 6, c = rc & 63;
      biasf[j] = (c < 49) ? rpb[relidx[r * 49 + c] * 3 + h] : 0.f;
    }
  }
}

// One block = one window. 4 waves. M(=49) tiled at row starts {0,16,32,33}
// (overlapping tiles recompute identical values; duplicate global stores masked).
__launch_bounds__(256, 2)
__global__ void attn_fused(const float* __restrict__ xg, const float* __restrict__ vg,
                           const float* __restrict__ bq, const float* __restrict__ bkv,
                           const float* __restrict__ bproj,
                           const unsigned short* __restrict__ wsT,
                           const float* __restrict__ biasf,
                           float* __restrict__ outg) {
  // LDS carve (bytes):
  //   [0      , 13328)  Xs  ushort[49][104]   -> reused as Ss float[49][68]
  //   [13328  , 23520)  Vs  ushort[49][104]   -> reused as OUTs (PV result, bf16)
  //   [23520  , 33712)  Qs  ushort[49][104]
  //   [33712  , 43904)  Ks  ushort[49][104]
  //   [43904  , 57728)  VVT ushort[96][72]    (v-transposed, keys 49..63 zeroed)
  //   [57728  , 64784)  Ps  ushort[49][72]    (attn probs bf16, cols 49..63 = 0)
  __shared__ __align__(16) unsigned char smem[64784];
  unsigned short* Xs  = (unsigned short*)smem;
  float*          Ss  = (float*)smem;
  unsigned short* Vs  = (unsigned short*)(smem + 13328);
  unsigned short* Qs  = (unsigned short*)(smem + 23520);
  unsigned short* Ks  = (unsigned short*)(smem + 33712);
  unsigned short* VVT = (unsigned short*)(smem + 43904);
  unsigned short* Ps  = (unsigned short*)(smem + 57728);

  const int tid = threadIdx.x;
  const int lane = tid & 63;
  const int wv = tid >> 6;       // wave 0..3
  const int c16 = lane & 15;
  const int g4 = lane >> 4;      // 0..3
  const int win = blockIdx.x;
  const float* xw = xg + (size_t)win * (NTOK * CDIM);
  const float* vw = vg + (size_t)win * (NTOK * CDIM);
  const int MST[4] = {0, 16, 32, 33};

  // ---- phase 0: stage x,v as bf16; zero VVT ----
  for (int i = tid; i < 2 * 1176; i += 256) {       // 49*96/4 = 1176 float4 each
    int which = i >= 1176;
    int j = which ? i - 1176 : i;
    int r = j / 24, c4 = (j - (j / 24) * 24) * 4;
    const float* src = which ? vw : xw;
    float4 f = *(const float4*)(src + r * 96 + c4);
    s16x4 p;
    p[0] = (short)f2bf(f.x); p[1] = (short)f2bf(f.y);
    p[2] = (short)f2bf(f.z); p[3] = (short)f2bf(f.w);
    *(s16x4*)((which ? Vs : Xs) + r * XS_S + c4) = p;
  }
  for (int i = tid; i < (96 * VT_S * 2) / 8; i += 256)   // 1728 qwords
    ((unsigned long long*)VVT)[i] = 0ull;
  __syncthreads();

  // ---- phase 1: Q/K/V projections ----
  bf16x8 axf[4][3], avf[4][3];
#pragma unroll
  for (int m = 0; m < 4; ++m)
#pragma unroll
    for (int k = 0; k < 3; ++k) {
      int off = (MST[m] + c16) * XS_S + k * 32 + g4 * 8;
      axf[m][k] = *(const bf16x8*)(Xs + off);
      avf[m][k] = *(const bf16x8*)(Vs + off);
    }
  const float scale = 0.17677669529663687f;  // 32^-0.5
  for (int nt = wv; nt < 18; nt += 4) {
    f32x4 acc[4] = {{0,0,0,0},{0,0,0,0},{0,0,0,0},{0,0,0,0}};
    const bool isq = nt < 6;
    const unsigned short* wbase = isq ? wsT : wsT + 9216;
    const int ocl = (isq ? nt * 16 : (nt - 6) * 16) + c16;   // output-channel row of wT
#pragma unroll
    for (int k = 0; k < 3; ++k) {
      bf16x8 b = *(const bf16x8*)(wbase + ocl * 96 + k * 32 + g4 * 8);
#pragma unroll
      for (int m = 0; m < 4; ++m)
        acc[m] = __builtin_amdgcn_mfma_f32_16x16x32_bf16(isq ? axf[m][k] : avf[m][k], b, acc[m], 0, 0, 0);
    }
    if (isq) {
      float bias = bq[ocl];
#pragma unroll
      for (int m = 0; m < 4; ++m) {
        int rb = MST[m] + g4 * 4;
#pragma unroll
        for (int r = 0; r < 4; ++r)
          Qs[(rb + r) * XS_S + ocl] = f2bf((acc[m][r] + bias) * scale);
      }
    } else if (nt < 12) {
      float bias = bkv[ocl];
#pragma unroll
      for (int m = 0; m < 4; ++m) {
        int rb = MST[m] + g4 * 4;
#pragma unroll
        for (int r = 0; r < 4; ++r)
          Ks[(rb + r) * XS_S + ocl] = f2bf(acc[m][r] + bias);
      }
    } else {
      float bias = bkv[ocl];
      int dim = ocl - 96;
#pragma unroll
      for (int m = 0; m < 4; ++m) {
        int rb = MST[m] + g4 * 4;
        if (m < 3) {                      // token base multiple of 4 -> aligned b64
          s16x4 p;
#pragma unroll
          for (int r = 0; r < 4; ++r) p[r] = (short)f2bf(acc[m][r] + bias);
          *(s16x4*)(VVT + dim * VT_S + rb) = p;
        } else {                          // mstart=33: odd token base, scalar writes
#pragma unroll
          for (int r = 0; r < 4; ++r)
            VVT[dim * VT_S + rb + r] = f2bf(acc[m][r] + bias);
        }
      }
    }
  }
  __syncthreads();

  // ---- per-head attention ----
  for (int h = 0; h < 3; ++h) {
    {  // S = Q @ K^T   (wave -> key tile)
      const int nstart = MST[wv];
      bf16x8 bk = *(const bf16x8*)(Ks + (nstart + c16) * XS_S + h * 32 + g4 * 8);
#pragma unroll
      for (int m = 0; m < 4; ++m) {
        bf16x8 aq = *(const bf16x8*)(Qs + (MST[m] + c16) * XS_S + h * 32 + g4 * 8);
        f32x4 s = __builtin_amdgcn_mfma_f32_16x16x32_bf16(aq, bk, (f32x4){0,0,0,0}, 0, 0, 0);
        int rb = MST[m] + g4 * 4;
#pragma unroll
        for (int r = 0; r < 4; ++r)
          Ss[(rb + r) * SS_S + nstart + c16] = s[r];
      }
    }
    __syncthreads();
    if (tid < 196) {  // softmax: 4 threads per query row
      int r = tid >> 2, c4 = tid & 3;
      const float* brow = biasf + (h * 49 + r) * 64 + c4 * 16;
      float vals[16];
#pragma unroll
      for (int jj = 0; jj < 4; ++jj) {
        f32x4 sv = *(const f32x4*)(Ss + r * SS_S + c4 * 16 + jj * 4);
        f32x4 bv = *(const f32x4*)(brow + jj * 4);
#pragma unroll
        for (int e = 0; e < 4; ++e) {
          int col = c4 * 16 + jj * 4 + e;
          vals[jj * 4 + e] = (col < 49) ? sv[e] + bv[e] : -1e30f;
        }
      }
      float mx = vals[0];
#pragma unroll
      for (int j = 1; j < 16; ++j) mx = fmaxf(mx, vals[j]);
      mx = fmaxf(mx, __shfl_xor(mx, 1, 4));
      mx = fmaxf(mx, __shfl_xor(mx, 2, 4));
      float sum = 0.f;
#pragma unroll
      for (int j = 0; j < 16; ++j) { vals[j] = __expf(vals[j] - mx); sum += vals[j]; }
      sum += __shfl_xor(sum, 1, 4);
      sum += __shfl_xor(sum, 2, 4);
      float rinv = 1.0f / sum;
      s16x8 w0, w1;
#pragma unroll
      for (int j = 0; j < 8; ++j) w0[j] = (short)f2bf(vals[j] * rinv);
#pragma unroll
      for (int j = 0; j < 8; ++j) w1[j] = (short)f2bf(vals[8 + j] * rinv);
      *(s16x8*)(Ps + r * PS_S + c4 * 16) = w0;
      *(s16x8*)(Ps + r * PS_S + c4 * 16 + 8) = w1;
    }
    __syncthreads();
    {  // OUT_h = P @ V   (wave -> query tile; B from VVT[n=dim][k=key])
      const int mstart = MST[wv];
      bf16x8 ap0 = *(const bf16x8*)(Ps + (mstart + c16) * PS_S + g4 * 8);
      bf16x8 ap1 = *(const bf16x8*)(Ps + (mstart + c16) * PS_S + 32 + g4 * 8);
#pragma unroll
      for (int n = 0; n < 2; ++n) {
        int dim = h * 32 + n * 16 + c16;
        bf16x8 bv0 = *(const bf16x8*)(VVT + dim * VT_S + g4 * 8);
        bf16x8 bv1 = *(const bf16x8*)(VVT + dim * VT_S + 32 + g4 * 8);
        f32x4 o = __builtin_amdgcn_mfma_f32_16x16x32_bf16(ap0, bv0, (f32x4){0,0,0,0}, 0, 0, 0);
        o = __builtin_amdgcn_mfma_f32_16x16x32_bf16(ap1, bv1, o, 0, 0, 0);
        int rb = mstart + g4 * 4;
#pragma unroll
        for (int r = 0; r < 4; ++r)
          Vs[(rb + r) * XS_S + dim] = f2bf(o[r]);   // OUTs lives in Vs region
      }
    }
    __syncthreads();
  }

  // ---- final projection: final^T = wprojT (A, global) x OUT^T (B = OUTs row-major) ----
  {
    const int nstart = MST[wv];           // token tile
    bf16x8 bo[3];
#pragma unroll
    for (int k = 0; k < 3; ++k)
      bo[k] = *(const bf16x8*)(Vs + (nstart + c16) * XS_S + k * 32 + g4 * 8);
    const unsigned short* wp = wsT + 27648;
    const bool store_ok = (wv < 3) || (c16 == 15);  // tile 3 only stores token 48
    const int token = nstart + c16;
    float* orow = outg + (size_t)win * (NTOK * CDIM) + token * 96;
#pragma unroll
    for (int mt = 0; mt < 6; ++mt) {
      f32x4 acc = {0, 0, 0, 0};
      int mrow = mt * 16 + c16;           // output channel row of wprojT
#pragma unroll
      for (int k = 0; k < 3; ++k) {
        bf16x8 a = *(const bf16x8*)(wp + mrow * 96 + k * 32 + g4 * 8);
        acc = __builtin_amdgcn_mfma_f32_16x16x32_bf16(a, bo[k], acc, 0, 0, 0);
      }
      int oc0 = mt * 16 + g4 * 4;
      if (store_ok) {
        float4 bb = *(const float4*)(bproj + oc0);
        float4 o4;
        o4.x = acc[0] + bb.x; o4.y = acc[1] + bb.y;
        o4.z = acc[2] + bb.z; o4.w = acc[3] + bb.w;
        *(float4*)(orow + oc0) = o4;
      }
    }
  }
}

extern "C" void kernel_launch(void* const* d_in, const int* in_sizes, int n_in,
                              void* d_out, int out_size, void* d_ws, size_t ws_size,
                              hipStream_t stream) {
  const float* x     = (const float*)d_in[0];
  const float* v     = (const float*)d_in[1];
  const float* wq    = (const float*)d_in[2];
  const float* bq    = (const float*)d_in[3];
  const float* wkv   = (const float*)d_in[4];
  const float* bkv   = (const float*)d_in[5];
  const float* wproj = (const float*)d_in[6];
  const float* bproj = (const float*)d_in[7];
  const float* rpb   = (const float*)d_in[8];
  const int*   relidx= (const int*)d_in[9];
  float* out = (float*)d_out;
  unsigned short* wsT = (unsigned short*)d_ws;
  float* biasf = (float*)((char*)d_ws + 73728);
  int nwin = in_sizes[0] / (NTOK * CDIM);   // 8192

  hipLaunchKernelGGL(prep, dim3(181), dim3(256), 0, stream,
                     wq, wkv, wproj, rpb, relidx, wsT, biasf);
  hipLaunchKernelGGL(attn_fused, dim3(nwin), dim3(256), 0, stream,
                     x, v, bq, bkv, bproj, wsT, biasf, out);
}

// Round 2
// 277.014 us; speedup vs baseline: 1.1834x; 1.1834x over previous
//
#include <hip/hip_runtime.h>
#include <hip/hip_bf16.h>

typedef __bf16 bf16x8 __attribute__((ext_vector_type(8)));
typedef float f32x4 __attribute__((ext_vector_type(4)));
typedef short s16x8 __attribute__((ext_vector_type(8)));
typedef short s16x4 __attribute__((ext_vector_type(4)));

#define NTOK 49
#define CDIM 96
#define XS_S 104   // bf16 row stride (208B) for staged x/v, Q, K, OUT — 16B aligned, conflict-free at g4*16B pattern
#define VT_S 72    // bf16 row stride (144B) for VVT
#define PW_S 72    // bf16 row stride for per-wave P staging

__device__ __forceinline__ unsigned short f2bf(float f) {
  __hip_bfloat16 h = __float2bfloat16(f);
  return __builtin_bit_cast(unsigned short, h);
}

// d_ws layout:
//   ushort[0      .. 9216 )  wqT   [oc 96][ic 96]   (bf16 bits)
//   ushort[9216   .. 27648)  wkvT  [oc 192][ic 96]
//   ushort[27648  .. 36864)  wprojT[oc 96][ic 96]
//   byte 73728: float biasf[3][49][64]  (rpb gathered, cols 49..63 = 0)
__global__ void prep(const float* __restrict__ wq, const float* __restrict__ wkv,
                     const float* __restrict__ wproj, const float* __restrict__ rpb,
                     const int* __restrict__ relidx, unsigned short* __restrict__ wsT,
                     float* __restrict__ biasf) {
  const int total = 36864 + 3 * 49 * 64;
  for (int i = blockIdx.x * 256 + threadIdx.x; i < total; i += gridDim.x * 256) {
    if (i < 9216) {
      int oc = i / 96, ic = i - oc * 96;
      wsT[i] = f2bf(wq[ic * 96 + oc]);
    } else if (i < 27648) {
      int j = i - 9216; int oc = j / 96, ic = j - oc * 96;
      wsT[i] = f2bf(wkv[ic * 192 + oc]);
    } else if (i < 36864) {
      int j = i - 27648; int oc = j / 96, ic = j - oc * 96;
      wsT[i] = f2bf(wproj[ic * 96 + oc]);
    } else {
      int j = i - 36864; int h = j / 3136; int rc = j - h * 3136;
      int r = rc >> 6, c = rc & 63;
      biasf[j] = (c < 49) ? rpb[relidx[r * 49 + c] * 3 + h] : 0.f;
    }
  }
}

// One block = one window, 4 waves, 3 blocks/CU.
// Barriers: stage | x-frag load | proj | attn-tasks | final-proj  (4 syncs).
// Attention: wave wv owns query tile qt=wv (starts {0,16,32,33}); per head:
// S^T = mfma(K_tile, Q_tile) puts all 64 key scores for ONE query in each
// lane (keys 16*kt+4*g4+r) -> in-register softmax (in-lane + shfl_xor 16/32),
// P transposed via per-wave private LDS bounce (in-wave lgkmcnt only).
__launch_bounds__(256, 3)
__global__ void attn_fused(const float* __restrict__ xg, const float* __restrict__ vg,
                           const float* __restrict__ bq, const float* __restrict__ bkv,
                           const float* __restrict__ bproj,
                           const unsigned short* __restrict__ wsT,
                           const float* __restrict__ biasf,
                           float* __restrict__ outg) {
  // LDS carve (bytes), total 53664 -> 3 blocks/CU:
  //   [0     ,10240)  Qs  ushort[49][104]
  //   [10240 ,20432)  Ks  ushort[49][104]  (S^T m-tile 3 reads rows 48..63: bleeds
  //                                         into Pw region -> garbage, masked in softmax)
  //   [20432 ,29648)  Pw  ushort[4][16][72]  per-wave P staging
  //   [29648 ,43472)  XV  x-stage ushort[49][104] -> VVT ushort[96][72] (v^T, cols=keys)
  //   [43472 ,53664)  Vs  v-stage ushort[49][104] -> OUTs ushort[49][104]
  __shared__ __align__(16) unsigned char smem[53664];
  unsigned short* Qs = (unsigned short*)(smem);
  unsigned short* Ks = (unsigned short*)(smem + 10240);
  unsigned short* Pw = (unsigned short*)(smem + 20432);
  unsigned short* XV = (unsigned short*)(smem + 29648);
  unsigned short* Vs = (unsigned short*)(smem + 43472);

  const int tid = threadIdx.x;
  const int lane = tid & 63;
  const int wv = tid >> 6;       // wave 0..3
  const int c16 = lane & 15;
  const int g4 = lane >> 4;      // 0..3
  const int win = blockIdx.x;
  const float* xw = xg + (size_t)win * (NTOK * CDIM);
  const float* vw = vg + (size_t)win * (NTOK * CDIM);
  const int MST[4] = {0, 16, 32, 33};

  // ---- phase 0: stage x -> XV, v -> Vs (bf16) ----
  for (int i = tid; i < 2 * 1176; i += 256) {       // 49*96/4 = 1176 float4 each
    int which = i >= 1176;
    int j = which ? i - 1176 : i;
    int r = j / 24, c4 = (j - r * 24) * 4;
    const float* src = which ? vw : xw;
    float4 f = *(const float4*)(src + r * 96 + c4);
    s16x4 p;
    p[0] = (short)f2bf(f.x); p[1] = (short)f2bf(f.y);
    p[2] = (short)f2bf(f.z); p[3] = (short)f2bf(f.w);
    *(s16x4*)((which ? Vs : XV) + r * XS_S + c4) = p;
  }
  __syncthreads();

  // ---- x fragments to registers (all waves), then XV region becomes VVT ----
  bf16x8 axf[4][3];
#pragma unroll
  for (int m = 0; m < 4; ++m)
#pragma unroll
    for (int k = 0; k < 3; ++k)
      axf[m][k] = *(const bf16x8*)(XV + (MST[m] + c16) * XS_S + k * 32 + g4 * 8);
  __syncthreads();

  unsigned short* VVT = XV;

  // ---- phase 1: Q/K/V projections (v-fragments loaded lazily from Vs) ----
  const float scale = 0.17677669529663687f;  // 32^-0.5
  for (int nt = wv; nt < 18; nt += 4) {
    f32x4 acc[4] = {{0,0,0,0},{0,0,0,0},{0,0,0,0},{0,0,0,0}};
    const bool isq = nt < 6;
    const unsigned short* wbase = isq ? wsT : wsT + 9216;
    const int ocl = (isq ? nt * 16 : (nt - 6) * 16) + c16;   // output-channel row of wT
#pragma unroll
    for (int k = 0; k < 3; ++k) {
      bf16x8 b = *(const bf16x8*)(wbase + ocl * 96 + k * 32 + g4 * 8);
      if (isq) {
#pragma unroll
        for (int m = 0; m < 4; ++m)
          acc[m] = __builtin_amdgcn_mfma_f32_16x16x32_bf16(axf[m][k], b, acc[m], 0, 0, 0);
      } else {
#pragma unroll
        for (int m = 0; m < 4; ++m) {
          bf16x8 av = *(const bf16x8*)(Vs + (MST[m] + c16) * XS_S + k * 32 + g4 * 8);
          acc[m] = __builtin_amdgcn_mfma_f32_16x16x32_bf16(av, b, acc[m], 0, 0, 0);
        }
      }
    }
    if (isq) {
      float bias = bq[ocl];
#pragma unroll
      for (int m = 0; m < 4; ++m) {
        int rb = MST[m] + g4 * 4;
#pragma unroll
        for (int r = 0; r < 4; ++r)
          Qs[(rb + r) * XS_S + ocl] = f2bf((acc[m][r] + bias) * scale);
      }
    } else if (nt < 12) {
      float bias = bkv[ocl];
#pragma unroll
      for (int m = 0; m < 4; ++m) {
        int rb = MST[m] + g4 * 4;
#pragma unroll
        for (int r = 0; r < 4; ++r)
          Ks[(rb + r) * XS_S + ocl] = f2bf(acc[m][r] + bias);
      }
    } else {
      float bias = bkv[ocl];
      int dim = ocl - 96;
#pragma unroll
      for (int m = 0; m < 4; ++m) {
        int rb = MST[m] + g4 * 4;
        if (m < 3) {                      // token base multiple of 4 -> aligned b64
          s16x4 p;
#pragma unroll
          for (int r = 0; r < 4; ++r) p[r] = (short)f2bf(acc[m][r] + bias);
          *(s16x4*)(VVT + dim * VT_S + rb) = p;
        } else {                          // mstart=33: odd token base, scalar writes
#pragma unroll
          for (int r = 0; r < 4; ++r)
            VVT[dim * VT_S + rb + r] = f2bf(acc[m][r] + bias);
        }
      }
    }
  }
  __syncthreads();

  // ---- attention: wave wv owns query tile qt=wv, loops over 3 heads ----
  const int q0 = MST[wv];
  unsigned short* mypw = Pw + wv * 16 * PW_S;
  unsigned short* OUTs = Vs;   // v-stage dead -> PV output

  // mask for V^T fragment keys 32+g4*8+j >= 49 (garbage VVT cols; NaN-safe zero)
  s16x8 vmask;
#pragma unroll
  for (int j = 0; j < 8; ++j)
    vmask[j] = (short)(((32 + g4 * 8 + j) < 49) ? 0xFFFF : 0x0000);

  for (int h = 0; h < 3; ++h) {
    // S^T: A = K key-tiles {0,16,32,48}, B = Q query tile -> C[key][query]
    bf16x8 bqf = *(const bf16x8*)(Qs + (q0 + c16) * XS_S + h * 32 + g4 * 8);
    f32x4 s[4];
#pragma unroll
    for (int kt = 0; kt < 4; ++kt) {
      bf16x8 ak = *(const bf16x8*)(Ks + (16 * kt + c16) * XS_S + h * 32 + g4 * 8);
      s[kt] = __builtin_amdgcn_mfma_f32_16x16x32_bf16(ak, bqf, (f32x4){0,0,0,0}, 0, 0, 0);
    }
    // in-register softmax: lane owns query q0+c16, keys 16*kt+4*g4+r
    const int q = q0 + c16;
    const float* brow = biasf + (h * 49 + q) * 64 + 4 * g4;
    float vals[16];
    float mx = -1e30f;
#pragma unroll
    for (int kt = 0; kt < 4; ++kt) {
      f32x4 bv = *(const f32x4*)(brow + 16 * kt);
#pragma unroll
      for (int r = 0; r < 4; ++r) {
        int key = 16 * kt + 4 * g4 + r;
        float vl = (kt < 3 || key < 49) ? (s[kt][r] + bv[r]) : -1e30f;
        vals[kt * 4 + r] = vl;
        mx = fmaxf(mx, vl);
      }
    }
    mx = fmaxf(mx, __shfl_xor(mx, 16, 64));
    mx = fmaxf(mx, __shfl_xor(mx, 32, 64));
    float sum = 0.f;
#pragma unroll
    for (int j = 0; j < 16; ++j) { vals[j] = __expf(vals[j] - mx); sum += vals[j]; }
    sum += __shfl_xor(sum, 16, 64);
    sum += __shfl_xor(sum, 32, 64);
    float rinv = 1.0f / sum;
    // P transpose bounce through per-wave LDS (masked keys are exactly 0)
#pragma unroll
    for (int kt = 0; kt < 4; ++kt) {
      s16x4 p;
#pragma unroll
      for (int r = 0; r < 4; ++r) p[r] = (short)f2bf(vals[kt * 4 + r] * rinv);
      *(s16x4*)(mypw + c16 * PW_S + 16 * kt + 4 * g4) = p;
    }
    asm volatile("s_waitcnt lgkmcnt(0)" ::: "memory");  // in-wave write->read
    bf16x8 ap0 = *(const bf16x8*)(mypw + c16 * PW_S + g4 * 8);
    bf16x8 ap1 = *(const bf16x8*)(mypw + c16 * PW_S + 32 + g4 * 8);
    // PV: A = P[q][key], B = VVT[dim][key] -> C[q][dim]
#pragma unroll
    for (int dt = 0; dt < 2; ++dt) {
      int dim = h * 32 + dt * 16 + c16;
      bf16x8 bv0 = *(const bf16x8*)(VVT + dim * VT_S + g4 * 8);
      s16x8 b1 = *(const s16x8*)(VVT + dim * VT_S + 32 + g4 * 8);
      b1 &= vmask;
      f32x4 o = __builtin_amdgcn_mfma_f32_16x16x32_bf16(ap0, bv0, (f32x4){0,0,0,0}, 0, 0, 0);
      o = __builtin_amdgcn_mfma_f32_16x16x32_bf16(ap1, __builtin_bit_cast(bf16x8, b1), o, 0, 0, 0);
#pragma unroll
      for (int r = 0; r < 4; ++r)
        OUTs[(q0 + 4 * g4 + r) * XS_S + dim] = f2bf(o[r]);
    }
  }
  __syncthreads();

  // ---- final projection: final^T = wprojT (A) x OUT^T (B = OUTs rows) ----
  {
    const int nstart = MST[wv];           // token tile
    bf16x8 bo[3];
#pragma unroll
    for (int k = 0; k < 3; ++k)
      bo[k] = *(const bf16x8*)(OUTs + (nstart + c16) * XS_S + k * 32 + g4 * 8);
    const unsigned short* wp = wsT + 27648;
    const bool store_ok = (wv < 3) || (c16 == 15);  // tile 3 only stores token 48
    const int token = nstart + c16;
    float* orow = outg + (size_t)win * (NTOK * CDIM) + token * 96;
#pragma unroll
    for (int mt = 0; mt < 6; ++mt) {
      f32x4 acc = {0, 0, 0, 0};
      int mrow = mt * 16 + c16;           // output channel row of wprojT
#pragma unroll
      for (int k = 0; k < 3; ++k) {
        bf16x8 a = *(const bf16x8*)(wp + mrow * 96 + k * 32 + g4 * 8);
        acc = __builtin_amdgcn_mfma_f32_16x16x32_bf16(a, bo[k], acc, 0, 0, 0);
      }
      int oc0 = mt * 16 + g4 * 4;
      if (store_ok) {
        float4 bb = *(const float4*)(bproj + oc0);
        float4 o4;
        o4.x = acc[0] + bb.x; o4.y = acc[1] + bb.y;
        o4.z = acc[2] + bb.z; o4.w = acc[3] + bb.w;
        *(float4*)(orow + oc0) = o4;
      }
    }
  }
}

extern "C" void kernel_launch(void* const* d_in, const int* in_sizes, int n_in,
                              void* d_out, int out_size, void* d_ws, size_t ws_size,
                              hipStream_t stream) {
  const float* x     = (const float*)d_in[0];
  const float* v     = (const float*)d_in[1];
  const float* wq    = (const float*)d_in[2];
  const float* bq    = (const float*)d_in[3];
  const float* wkv   = (const float*)d_in[4];
  const float* bkv   = (const float*)d_in[5];
  const float* wproj = (const float*)d_in[6];
  const float* bproj = (const float*)d_in[7];
  const float* rpb   = (const float*)d_in[8];
  const int*   relidx= (const int*)d_in[9];
  float* out = (float*)d_out;
  unsigned short* wsT = (unsigned short*)d_ws;
  float* biasf = (float*)((char*)d_ws + 73728);
  int nwin = in_sizes[0] / (NTOK * CDIM);   // 8192

  hipLaunchKernelGGL(prep, dim3(181), dim3(256), 0, stream,
                     wq, wkv, wproj, rpb, relidx, wsT, biasf);
  hipLaunchKernelGGL(attn_fused, dim3(nwin), dim3(256), 0, stream,
                     x, v, bq, bkv, bproj, wsT, biasf, out);
}

// Round 3
// 258.709 us; speedup vs baseline: 1.2671x; 1.0708x over previous
//
#include <hip/hip_runtime.h>
#include <hip/hip_bf16.h>

typedef __bf16 bf16x8 __attribute__((ext_vector_type(8)));
typedef float f32x4 __attribute__((ext_vector_type(4)));
typedef short s16x8 __attribute__((ext_vector_type(8)));
typedef short s16x4 __attribute__((ext_vector_type(4)));

#define NTOK 49
#define CDIM 96
#define KS_S 104   // Ks row stride (ushort), 208B
#define VT_S 72    // VVT row stride (ushort), 144B
#define BN_S 104   // per-wave bounce row stride (ushort)

__device__ __forceinline__ unsigned short f2bf(float f) {
  __hip_bfloat16 h = __float2bfloat16(f);
  return __builtin_bit_cast(unsigned short, h);
}

// load 8 consecutive floats from global, convert to bf16x8
__device__ __forceinline__ bf16x8 ld_cvt8(const float* p) {
  float4 a = *(const float4*)p;
  float4 b = *(const float4*)(p + 4);
  s16x8 r;
  r[0] = (short)f2bf(a.x); r[1] = (short)f2bf(a.y);
  r[2] = (short)f2bf(a.z); r[3] = (short)f2bf(a.w);
  r[4] = (short)f2bf(b.x); r[5] = (short)f2bf(b.y);
  r[6] = (short)f2bf(b.z); r[7] = (short)f2bf(b.w);
  return __builtin_bit_cast(bf16x8, r);
}

// d_ws layout:
//   ushort[0      .. 9216 )  wqT   [oc 96][ic 96]   (bf16 bits)
//   ushort[9216   .. 27648)  wkvT  [oc 192][ic 96]
//   ushort[27648  .. 36864)  wprojT[oc 96][ic 96]
//   byte 73728: float biasf[3][49][64]  (rpb gathered, cols 49..63 = 0)
__global__ void prep(const float* __restrict__ wq, const float* __restrict__ wkv,
                     const float* __restrict__ wproj, const float* __restrict__ rpb,
                     const int* __restrict__ relidx, unsigned short* __restrict__ wsT,
                     float* __restrict__ biasf) {
  const int total = 36864 + 3 * 49 * 64;
  for (int i = blockIdx.x * 256 + threadIdx.x; i < total; i += gridDim.x * 256) {
    if (i < 9216) {
      int oc = i / 96, ic = i - oc * 96;
      wsT[i] = f2bf(wq[ic * 96 + oc]);
    } else if (i < 27648) {
      int j = i - 9216; int oc = j / 96, ic = j - oc * 96;
      wsT[i] = f2bf(wkv[ic * 192 + oc]);
    } else if (i < 36864) {
      int j = i - 27648; int oc = j / 96, ic = j - oc * 96;
      wsT[i] = f2bf(wproj[ic * 96 + oc]);
    } else {
      int j = i - 36864; int h = j / 3136; int rc = j - h * 3136;
      int r = rc >> 6, c = rc & 63;
      biasf[j] = (c < 49) ? rpb[relidx[r * 49 + c] * 3 + h] : 0.f;
    }
  }
}

// One block = one window, 4 waves, ONE barrier. Wave wv owns token tile
// starting q0 in {0,16,32,33} (overlap rows recompute bit-identical values).
// Per wave: x,v fragments direct from global; Q private (regs via per-wave
// bounce transpose); K->Ks, V^T->VVT shared; barrier; per head
// S^T=mfma(K,Q) -> in-register softmax -> P bounce -> PV -> OUT bounce ->
// per-head out-proj accumulated in fp32 regs; masked float4 stores.
__launch_bounds__(256, 4)
__global__ void attn_fused(const float* __restrict__ xg, const float* __restrict__ vg,
                           const float* __restrict__ bq, const float* __restrict__ bkv,
                           const float* __restrict__ bproj,
                           const unsigned short* __restrict__ wsT,
                           const float* __restrict__ biasf,
                           float* __restrict__ outg) {
  // LDS (bytes): [0,10192) Ks[49][104]  (rows 49..63 bleed-READ into VVT: garbage, masked)
  //              [10192,24016) VVT[96][72]  (v^T, cols=tokens; cols 49..63 never written -> vmask)
  //              [24016,37328) bounce[4 waves][16][104]
  __shared__ __align__(16) unsigned char smem[37328];
  unsigned short* Ks  = (unsigned short*)smem;
  unsigned short* VVT = (unsigned short*)(smem + 10192);

  const int tid = threadIdx.x;
  const int lane = tid & 63;
  const int wv = tid >> 6;
  const int c16 = lane & 15;
  const int g4 = lane >> 4;
  const int win = blockIdx.x;
  const int q0 = (wv == 0) ? 0 : (wv == 1) ? 16 : (wv == 2) ? 32 : 33;
  unsigned short* bnc = (unsigned short*)(smem + 24016) + wv * (16 * BN_S);

  const float* xrow = xg + (size_t)win * (NTOK * CDIM) + (q0 + c16) * CDIM;
  const float* vrow = vg + (size_t)win * (NTOK * CDIM) + (q0 + c16) * CDIM;

  // ---- x fragments (own 16 query rows) + Q projection -> bounce ----
  bf16x8 xf[3];
#pragma unroll
  for (int k = 0; k < 3; ++k) xf[k] = ld_cvt8(xrow + k * 32 + g4 * 8);
  const float scale = 0.17677669529663687f;  // 32^-0.5
#pragma unroll
  for (int nt = 0; nt < 6; ++nt) {
    f32x4 acc = {0, 0, 0, 0};
    const int ocl = nt * 16 + c16;
#pragma unroll
    for (int k = 0; k < 3; ++k) {
      bf16x8 b = *(const bf16x8*)(wsT + ocl * 96 + k * 32 + g4 * 8);
      acc = __builtin_amdgcn_mfma_f32_16x16x32_bf16(xf[k], b, acc, 0, 0, 0);
    }
    float bias = bq[ocl];
#pragma unroll
    for (int r = 0; r < 4; ++r)
      bnc[(4 * g4 + r) * BN_S + ocl] = f2bf((acc[r] + bias) * scale);
  }

  // ---- v fragments (own 16 token rows) + K/V projections -> shared LDS ----
  bf16x8 vf[3];
#pragma unroll
  for (int k = 0; k < 3; ++k) vf[k] = ld_cvt8(vrow + k * 32 + g4 * 8);
#pragma unroll
  for (int nt = 0; nt < 12; ++nt) {
    f32x4 acc = {0, 0, 0, 0};
    const int ocl = nt * 16 + c16;
#pragma unroll
    for (int k = 0; k < 3; ++k) {
      bf16x8 b = *(const bf16x8*)(wsT + 9216 + ocl * 96 + k * 32 + g4 * 8);
      acc = __builtin_amdgcn_mfma_f32_16x16x32_bf16(vf[k], b, acc, 0, 0, 0);
    }
    float bias = bkv[ocl];
    if (nt < 6) {                    // K rows (tokens q0+4g4+r), col ocl
#pragma unroll
      for (int r = 0; r < 4; ++r)
        Ks[(q0 + 4 * g4 + r) * KS_S + ocl] = f2bf(acc[r] + bias);
    } else {                         // V^T: row dim, cols = tokens q0+4g4..+3
      int dim = ocl - 96;
      int rb = q0 + 4 * g4;
      if (wv < 3) {                  // rb multiple of 4 -> aligned b64
        s16x4 p;
#pragma unroll
        for (int r = 0; r < 4; ++r) p[r] = (short)f2bf(acc[r] + bias);
        *(s16x4*)(VVT + dim * VT_S + rb) = p;
      } else {                       // q0=33: odd base, scalar writes
#pragma unroll
        for (int r = 0; r < 4; ++r)
          VVT[dim * VT_S + rb + r] = f2bf(acc[r] + bias);
      }
    }
  }
  __syncthreads();   // the only barrier (also drains Q-bounce writes)

  // ---- Q fragments from private bounce ----
  bf16x8 qf[3];
#pragma unroll
  for (int h = 0; h < 3; ++h)
    qf[h] = *(const bf16x8*)(bnc + c16 * BN_S + h * 32 + g4 * 8);

  // mask for V^T fragment keys 32+g4*8+j >= 49 (unwritten VVT cols; NaN-safe)
  s16x8 vmask;
#pragma unroll
  for (int j = 0; j < 8; ++j)
    vmask[j] = (short)(((32 + g4 * 8 + j) < 49) ? 0xFFFF : 0x0000);

  f32x4 oacc[6] = {{0,0,0,0},{0,0,0,0},{0,0,0,0},{0,0,0,0},{0,0,0,0},{0,0,0,0}};

  for (int h = 0; h < 3; ++h) {
    // S^T: A = K key-tiles {0,16,32,48}, B = Q -> C[key][query]
    f32x4 s[4];
#pragma unroll
    for (int kt = 0; kt < 4; ++kt) {
      bf16x8 ak = *(const bf16x8*)(Ks + (16 * kt + c16) * KS_S + h * 32 + g4 * 8);
      s[kt] = __builtin_amdgcn_mfma_f32_16x16x32_bf16(ak, qf[h], (f32x4){0,0,0,0}, 0, 0, 0);
    }
    // in-register softmax: lane owns query q0+c16, keys 16*kt+4*g4+r
    const int q = q0 + c16;
    const float* brow = biasf + (h * 49 + q) * 64 + 4 * g4;
    float vals[16];
    float mx = -1e30f;
#pragma unroll
    for (int kt = 0; kt < 4; ++kt) {
      f32x4 bv = *(const f32x4*)(brow + 16 * kt);
#pragma unroll
      for (int r = 0; r < 4; ++r) {
        int key = 16 * kt + 4 * g4 + r;
        float vl = (kt < 3 || key < 49) ? (s[kt][r] + bv[r]) : -1e30f;
        vals[kt * 4 + r] = vl;
        mx = fmaxf(mx, vl);
      }
    }
    mx = fmaxf(mx, __shfl_xor(mx, 16, 64));
    mx = fmaxf(mx, __shfl_xor(mx, 32, 64));
    float sum = 0.f;
#pragma unroll
    for (int j = 0; j < 16; ++j) { vals[j] = __expf(vals[j] - mx); sum += vals[j]; }
    sum += __shfl_xor(sum, 16, 64);
    sum += __shfl_xor(sum, 32, 64);
    float rinv = 1.0f / sum;
    // P -> per-wave bounce (transpose to [query][key] rows)
#pragma unroll
    for (int kt = 0; kt < 4; ++kt) {
      s16x4 p;
#pragma unroll
      for (int r = 0; r < 4; ++r) p[r] = (short)f2bf(vals[kt * 4 + r] * rinv);
      *(s16x4*)(bnc + c16 * BN_S + 16 * kt + 4 * g4) = p;
    }
    asm volatile("s_waitcnt lgkmcnt(0)" ::: "memory");
    __builtin_amdgcn_sched_barrier(0);
    bf16x8 ap0 = *(const bf16x8*)(bnc + c16 * BN_S + g4 * 8);
    bf16x8 ap1 = *(const bf16x8*)(bnc + c16 * BN_S + 32 + g4 * 8);
    // PV: A = P[query][key], B = VVT[dim][key] -> C[query][dim]; bounce OUT_h
#pragma unroll
    for (int dt = 0; dt < 2; ++dt) {
      int dim = h * 32 + dt * 16 + c16;
      bf16x8 bv0 = *(const bf16x8*)(VVT + dim * VT_S + g4 * 8);
      s16x8 b1 = *(const s16x8*)(VVT + dim * VT_S + 32 + g4 * 8);
      b1 &= vmask;
      f32x4 o = __builtin_amdgcn_mfma_f32_16x16x32_bf16(ap0, bv0, (f32x4){0,0,0,0}, 0, 0, 0);
      o = __builtin_amdgcn_mfma_f32_16x16x32_bf16(ap1, __builtin_bit_cast(bf16x8, b1), o, 0, 0, 0);
#pragma unroll
      for (int r = 0; r < 4; ++r)
        bnc[(4 * g4 + r) * BN_S + dt * 16 + c16] = f2bf(o[r]);  // OUT_h[token][head-dim]
    }
    asm volatile("s_waitcnt lgkmcnt(0)" ::: "memory");
    __builtin_amdgcn_sched_barrier(0);
    // per-head out-projection: out^T += wprojT_h (A) x OUT_h^T (B)
    bf16x8 bo = *(const bf16x8*)(bnc + c16 * BN_S + g4 * 8);
#pragma unroll
    for (int mt = 0; mt < 6; ++mt) {
      bf16x8 a = *(const bf16x8*)(wsT + 27648 + (mt * 16 + c16) * 96 + h * 32 + g4 * 8);
      oacc[mt] = __builtin_amdgcn_mfma_f32_16x16x32_bf16(a, bo, oacc[mt], 0, 0, 0);
    }
    asm volatile("s_waitcnt lgkmcnt(0)" ::: "memory");  // bo consumed before next head's P overwrites
    __builtin_amdgcn_sched_barrier(0);
  }

  // ---- store: lane holds out[oc=mt*16+4g4+r][token=q0+c16] ----
  {
    const bool store_ok = (wv < 3) || (c16 == 15);  // tile 3 only stores token 48
    const int token = q0 + c16;
    float* orow = outg + (size_t)win * (NTOK * CDIM) + token * 96;
#pragma unroll
    for (int mt = 0; mt < 6; ++mt) {
      int oc0 = mt * 16 + g4 * 4;
      if (store_ok) {
        float4 bb = *(const float4*)(bproj + oc0);
        float4 o4;
        o4.x = oacc[mt][0] + bb.x; o4.y = oacc[mt][1] + bb.y;
        o4.z = oacc[mt][2] + bb.z; o4.w = oacc[mt][3] + bb.w;
        *(float4*)(orow + oc0) = o4;
      }
    }
  }
}

extern "C" void kernel_launch(void* const* d_in, const int* in_sizes, int n_in,
                              void* d_out, int out_size, void* d_ws, size_t ws_size,
                              hipStream_t stream) {
  const float* x     = (const float*)d_in[0];
  const float* v     = (const float*)d_in[1];
  const float* wq    = (const float*)d_in[2];
  const float* bq    = (const float*)d_in[3];
  const float* wkv   = (const float*)d_in[4];
  const float* bkv   = (const float*)d_in[5];
  const float* wproj = (const float*)d_in[6];
  const float* bproj = (const float*)d_in[7];
  const float* rpb   = (const float*)d_in[8];
  const int*   relidx= (const int*)d_in[9];
  float* out = (float*)d_out;
  unsigned short* wsT = (unsigned short*)d_ws;
  float* biasf = (float*)((char*)d_ws + 73728);
  int nwin = in_sizes[0] / (NTOK * CDIM);   // 8192

  hipLaunchKernelGGL(prep, dim3(181), dim3(256), 0, stream,
                     wq, wkv, wproj, rpb, relidx, wsT, biasf);
  hipLaunchKernelGGL(attn_fused, dim3(nwin), dim3(256), 0, stream,
                     x, v, bq, bkv, bproj, wsT, biasf, out);
}

// Round 5
// 251.045 us; speedup vs baseline: 1.3058x; 1.0305x over previous
//
#include <hip/hip_runtime.h>
#include <hip/hip_bf16.h>

typedef __bf16 bf16x8 __attribute__((ext_vector_type(8)));
typedef float f32x4 __attribute__((ext_vector_type(4)));
typedef short s16x8 __attribute__((ext_vector_type(8)));
typedef short s16x4 __attribute__((ext_vector_type(4)));

#define NTOK 49
#define CDIM 96
#define KS_S 104   // Ks row stride (ushort), 208B = 13*16
#define VT_S 56    // VVT row stride (ushort), 112B = 7*16
#define BN_S 136   // bounce row stride (ushort), 272B = 17*16
#define LOG2E 1.4426950408889634f

#if __has_builtin(__builtin_amdgcn_exp2f)
#define EXP2F(x) __builtin_amdgcn_exp2f(x)
#else
#define EXP2F(x) exp2f(x)
#endif

#define DRAIN() do { asm volatile("s_waitcnt lgkmcnt(0)" ::: "memory"); \
                     __builtin_amdgcn_sched_barrier(0); } while (0)

__device__ __forceinline__ unsigned short f2bf(float f) {
  __hip_bfloat16 h = __float2bfloat16(f);
  return __builtin_bit_cast(unsigned short, h);
}

// load 8 consecutive floats from global, convert to bf16x8
__device__ __forceinline__ bf16x8 ld_cvt8(const float* p) {
  float4 a = *(const float4*)p;
  float4 b = *(const float4*)(p + 4);
  s16x8 r;
  r[0] = (short)f2bf(a.x); r[1] = (short)f2bf(a.y);
  r[2] = (short)f2bf(a.z); r[3] = (short)f2bf(a.w);
  r[4] = (short)f2bf(b.x); r[5] = (short)f2bf(b.y);
  r[6] = (short)f2bf(b.z); r[7] = (short)f2bf(b.w);
  return __builtin_bit_cast(bf16x8, r);
}

// d_ws layout:
//   ushort[0      .. 9216 )  wqT   [oc 96][ic 96]   (bf16 bits)
//   ushort[9216   .. 27648)  wkvT  [oc 192][ic 96]
//   ushort[27648  .. 36864)  wprojT[oc 96][ic 96]
//   byte 73728: float biasf[3][49][64]  (rpb gathered * log2e, cols 49..63 = 0)
__global__ void prep(const float* __restrict__ wq, const float* __restrict__ wkv,
                     const float* __restrict__ wproj, const float* __restrict__ rpb,
                     const int* __restrict__ relidx, unsigned short* __restrict__ wsT,
                     float* __restrict__ biasf) {
  const int total = 36864 + 3 * 49 * 64;
  for (int i = blockIdx.x * 256 + threadIdx.x; i < total; i += gridDim.x * 256) {
    if (i < 9216) {
      int oc = i / 96, ic = i - oc * 96;
      wsT[i] = f2bf(wq[ic * 96 + oc]);
    } else if (i < 27648) {
      int j = i - 9216; int oc = j / 96, ic = j - oc * 96;
      wsT[i] = f2bf(wkv[ic * 192 + oc]);
    } else if (i < 36864) {
      int j = i - 27648; int oc = j / 96, ic = j - oc * 96;
      wsT[i] = f2bf(wproj[ic * 96 + oc]);
    } else {
      int j = i - 36864; int h = j / 3136; int rc = j - h * 3136;
      int r = rc >> 6, c = rc & 63;
      biasf[j] = (c < 49) ? rpb[relidx[r * 49 + c] * 3 + h] * LOG2E : 0.f;
    }
  }
}

// One block = one window, 4 waves, ONE __syncthreads + 3 counted in-wave drains.
// Wave wv: query tile q0 in {0,16,32,33}; KV-proj split (K/V half x token-tile
// pair) so each wave reads only half of wkv. Attention: 3 heads batched,
// in-register softmax (exp2 domain), P/OUT through bounce columns scheduled so
// every write is issued after the last read of its region (in-order LDS):
//   P0->0..63  P1->64..127 | OUT0->0..31 OUT1->32..63 P2->64..127 |
//   OUT2->96..127 (after P2 ap1 read). fp32 register out-proj accumulator.
__launch_bounds__(256, 4)
__global__ void attn_fused(const float* __restrict__ xg, const float* __restrict__ vg,
                           const float* __restrict__ bq, const float* __restrict__ bkv,
                           const float* __restrict__ bproj,
                           const unsigned short* __restrict__ wsT,
                           const float* __restrict__ biasf,
                           float* __restrict__ outg) {
  // LDS (bytes): [0,10192) Ks[49][104] (rows 49..63 bleed-read -> garbage, masked)
  //              [10192,20944) VVT[96][56] (v^T; cols 49.. unwritten -> vmask)
  //              [20944,38352) bounce[4 waves][16][136]
  __shared__ __align__(16) unsigned char smem[38352];
  unsigned short* Ks  = (unsigned short*)smem;
  unsigned short* VVT = (unsigned short*)(smem + 10192);

  const int tid = threadIdx.x;
  const int lane = tid & 63;
  const int wv = tid >> 6;
  const int c16 = lane & 15;
  const int g4 = lane >> 4;
  const int win = blockIdx.x;
  const int q0 = (wv == 0) ? 0 : (wv == 1) ? 16 : (wv == 2) ? 32 : 33;
  unsigned short* bnc = (unsigned short*)(smem + 20944) + wv * (16 * BN_S);

  // KV-proj task: wave = (K/V half, token-tile pair)
  const int mp = wv & 1;
  const bool isK = (wv < 2);
  const int m0 = mp ? 32 : 0;
  const int m1 = mp ? 33 : 16;

  const float* base = xg + (size_t)win * (NTOK * CDIM);
  const float* vbase = vg + (size_t)win * (NTOK * CDIM);
  const float* xrow = base + (q0 + c16) * CDIM;
  const float* vrow0 = vbase + (m0 + c16) * CDIM;
  const float* vrow1 = vbase + (m1 + c16) * CDIM;

  // ---- direct global->reg fragment loads ----
  bf16x8 xf[3], vf0[3], vf1[3];
#pragma unroll
  for (int k = 0; k < 3; ++k) {
    xf[k]  = ld_cvt8(xrow  + k * 32 + g4 * 8);
    vf0[k] = ld_cvt8(vrow0 + k * 32 + g4 * 8);
    vf1[k] = ld_cvt8(vrow1 + k * 32 + g4 * 8);
  }

  // ---- Q projection (own tile) -> bounce cols 0..95; scale includes log2e ----
  const float scale = 0.2550348742f;  // 32^-0.5 * log2(e)
#pragma unroll
  for (int nt = 0; nt < 6; ++nt) {
    f32x4 acc = {0, 0, 0, 0};
    const int ocl = nt * 16 + c16;
#pragma unroll
    for (int k = 0; k < 3; ++k) {
      bf16x8 b = *(const bf16x8*)(wsT + ocl * 96 + k * 32 + g4 * 8);
      acc = __builtin_amdgcn_mfma_f32_16x16x32_bf16(xf[k], b, acc, 0, 0, 0);
    }
    float bias = bq[ocl];
#pragma unroll
    for (int r = 0; r < 4; ++r)
      bnc[(4 * g4 + r) * BN_S + ocl] = f2bf((acc[r] + bias) * scale);
  }

  // ---- K/V projection: own oc-half for two token tiles ----
#pragma unroll
  for (int nt = 0; nt < 6; ++nt) {
    const int ocl = (isK ? 0 : 96) + nt * 16 + c16;
    f32x4 a0 = {0, 0, 0, 0}, a1 = {0, 0, 0, 0};
#pragma unroll
    for (int k = 0; k < 3; ++k) {
      bf16x8 b = *(const bf16x8*)(wsT + 9216 + ocl * 96 + k * 32 + g4 * 8);
      a0 = __builtin_amdgcn_mfma_f32_16x16x32_bf16(vf0[k], b, a0, 0, 0, 0);
      a1 = __builtin_amdgcn_mfma_f32_16x16x32_bf16(vf1[k], b, a1, 0, 0, 0);
    }
    float bias = bkv[ocl];
    if (isK) {
#pragma unroll
      for (int r = 0; r < 4; ++r)
        Ks[(m0 + 4 * g4 + r) * KS_S + ocl] = f2bf(a0[r] + bias);
#pragma unroll
      for (int r = 0; r < 4; ++r)
        Ks[(m1 + 4 * g4 + r) * KS_S + ocl] = f2bf(a1[r] + bias);
    } else {
      int dim = ocl - 96;
      s16x4 p0;
#pragma unroll
      for (int r = 0; r < 4; ++r) p0[r] = (short)f2bf(a0[r] + bias);
      *(s16x4*)(VVT + dim * VT_S + (m0 + 4 * g4)) = p0;
      if (mp == 0) {
        s16x4 p1;
#pragma unroll
        for (int r = 0; r < 4; ++r) p1[r] = (short)f2bf(a1[r] + bias);
        *(s16x4*)(VVT + dim * VT_S + (16 + 4 * g4)) = p1;
      } else {
#pragma unroll
        for (int r = 0; r < 4; ++r)
          VVT[dim * VT_S + 33 + 4 * g4 + r] = f2bf(a1[r] + bias);
      }
    }
  }
  __syncthreads();   // the only block barrier

  // ---- attention: 3 heads batched ----
  const int q = q0 + c16;

  // mask for V^T fragment keys 32+g4*8+j >= 49 (unwritten VVT cols; NaN-safe)
  s16x8 vmask;
#pragma unroll
  for (int j = 0; j < 8; ++j)
    vmask[j] = (short)(((32 + g4 * 8 + j) < 49) ? 0xFFFF : 0x0000);

  f32x4 oacc[6] = {{0,0,0,0},{0,0,0,0},{0,0,0,0},{0,0,0,0},{0,0,0,0},{0,0,0,0}};

  // in-register softmax (exp2 domain) + P write to bounce cols [pcol, pcol+64)
  auto softmax_pw = [&](const f32x4* s, const f32x4* bv, int pcol) {
    float vals[16];
#pragma unroll
    for (int kt = 0; kt < 4; ++kt)
#pragma unroll
      for (int r = 0; r < 4; ++r) {
        int key = 16 * kt + 4 * g4 + r;
        vals[kt * 4 + r] = (kt < 3 || key < 49) ? (s[kt][r] + bv[kt][r]) : -1e30f;
      }
    float m8[8];
#pragma unroll
    for (int j = 0; j < 8; ++j) m8[j] = fmaxf(vals[j], vals[j + 8]);
    float ma = fmaxf(m8[0], m8[4]), mb = fmaxf(m8[1], m8[5]);
    float mc = fmaxf(m8[2], m8[6]), md = fmaxf(m8[3], m8[7]);
    float mx = fmaxf(fmaxf(ma, mb), fmaxf(mc, md));
    mx = fmaxf(mx, __shfl_xor(mx, 16, 64));
    mx = fmaxf(mx, __shfl_xor(mx, 32, 64));
    float e[16];
#pragma unroll
    for (int j = 0; j < 16; ++j) e[j] = EXP2F(vals[j] - mx);
    float s8[8];
#pragma unroll
    for (int j = 0; j < 8; ++j) s8[j] = e[j] + e[j + 8];
    float sa = s8[0] + s8[4], sb = s8[1] + s8[5], sc = s8[2] + s8[6], sd = s8[3] + s8[7];
    float sum = (sa + sb) + (sc + sd);
    sum += __shfl_xor(sum, 16, 64);
    sum += __shfl_xor(sum, 32, 64);
    float rinv = 1.0f / sum;
#pragma unroll
    for (int kt = 0; kt < 4; ++kt) {
      s16x4 p;
#pragma unroll
      for (int r = 0; r < 4; ++r) p[r] = (short)f2bf(e[kt * 4 + r] * rinv);
      *(s16x4*)(bnc + c16 * BN_S + pcol + 16 * kt + 4 * g4) = p;
    }
  };

  // P read + PV + OUT_h write to bounce cols [ocol, ocol+32)
  auto pv_out = [&](int h, int pcol, int ocol) {
    bf16x8 ap0 = *(const bf16x8*)(bnc + c16 * BN_S + pcol + g4 * 8);
    bf16x8 ap1 = *(const bf16x8*)(bnc + c16 * BN_S + pcol + 32 + g4 * 8);
#pragma unroll
    for (int dt = 0; dt < 2; ++dt) {
      int dim = h * 32 + dt * 16 + c16;
      bf16x8 bv0 = *(const bf16x8*)(VVT + dim * VT_S + g4 * 8);
      s16x8 b1 = *(const s16x8*)(VVT + dim * VT_S + 32 + g4 * 8);
      b1 &= vmask;
      f32x4 o = __builtin_amdgcn_mfma_f32_16x16x32_bf16(ap0, bv0, (f32x4){0,0,0,0}, 0, 0, 0);
      o = __builtin_amdgcn_mfma_f32_16x16x32_bf16(ap1, __builtin_bit_cast(bf16x8, b1), o, 0, 0, 0);
#pragma unroll
      for (int r = 0; r < 4; ++r)
        bnc[(4 * g4 + r) * BN_S + ocol + dt * 16 + c16] = f2bf(o[r]);
    }
  };

  // OUT_h read + out-projection accumulate
  auto oproj = [&](int h, int ocol) {
    bf16x8 bo = *(const bf16x8*)(bnc + c16 * BN_S + ocol + g4 * 8);
#pragma unroll
    for (int mt = 0; mt < 6; ++mt) {
      bf16x8 a = *(const bf16x8*)(wsT + 27648 + (mt * 16 + c16) * 96 + h * 32 + g4 * 8);
      oacc[mt] = __builtin_amdgcn_mfma_f32_16x16x32_bf16(a, bo, oacc[mt], 0, 0, 0);
    }
  };

  // bias prefetch h0,h1 (covers under QK MFMAs)
  f32x4 b0v[4], b1v[4];
  {
    const float* br0 = biasf + q * 64 + 4 * g4;
    const float* br1 = biasf + (49 + q) * 64 + 4 * g4;
#pragma unroll
    for (int kt = 0; kt < 4; ++kt) {
      b0v[kt] = *(const f32x4*)(br0 + 16 * kt);
      b1v[kt] = *(const f32x4*)(br1 + 16 * kt);
    }
  }
  // Q fragments from private bounce (cols 0..95; all reads issued before any P write)
  bf16x8 qf0 = *(const bf16x8*)(bnc + c16 * BN_S + g4 * 8);
  bf16x8 qf1 = *(const bf16x8*)(bnc + c16 * BN_S + 32 + g4 * 8);
  bf16x8 qf2 = *(const bf16x8*)(bnc + c16 * BN_S + 64 + g4 * 8);

  // QK^T heads 0,1: A = K key-tiles, B = Q -> C[key][query]
  f32x4 s0[4], s1[4];
#pragma unroll
  for (int kt = 0; kt < 4; ++kt) {
    bf16x8 ak = *(const bf16x8*)(Ks + (16 * kt + c16) * KS_S + g4 * 8);
    s0[kt] = __builtin_amdgcn_mfma_f32_16x16x32_bf16(ak, qf0, (f32x4){0,0,0,0}, 0, 0, 0);
  }
#pragma unroll
  for (int kt = 0; kt < 4; ++kt) {
    bf16x8 ak = *(const bf16x8*)(Ks + (16 * kt + c16) * KS_S + 32 + g4 * 8);
    s1[kt] = __builtin_amdgcn_mfma_f32_16x16x32_bf16(ak, qf1, (f32x4){0,0,0,0}, 0, 0, 0);
  }
  softmax_pw(s0, b0v, 0);    // P0 -> cols 0..63   (Q reads already issued)
  softmax_pw(s1, b1v, 64);   // P1 -> cols 64..127

  // QK^T head 2 + bias h2
  f32x4 b2v[4];
  {
    const float* br2 = biasf + (98 + q) * 64 + 4 * g4;
#pragma unroll
    for (int kt = 0; kt < 4; ++kt) b2v[kt] = *(const f32x4*)(br2 + 16 * kt);
  }
  f32x4 s2[4];
#pragma unroll
  for (int kt = 0; kt < 4; ++kt) {
    bf16x8 ak = *(const bf16x8*)(Ks + (16 * kt + c16) * KS_S + 64 + g4 * 8);
    s2[kt] = __builtin_amdgcn_mfma_f32_16x16x32_bf16(ak, qf2, (f32x4){0,0,0,0}, 0, 0, 0);
  }

  DRAIN();                   // P0,P1 visible
  pv_out(0, 0, 0);           // reads P0 (0..63),  writes OUT0 -> 0..31
  pv_out(1, 64, 32);         // reads P1 (64..127), writes OUT1 -> 32..63
  softmax_pw(s2, b2v, 64);   // P2 -> 64..127 (P1 reads issued above)

  DRAIN();                   // OUT0, OUT1, P2 visible
  oproj(0, 0);
  oproj(1, 32);
  pv_out(2, 64, 96);         // reads P2 (64..127), writes OUT2 -> 96..127 (after ap1 read)

  DRAIN();                   // OUT2 visible
  oproj(2, 96);

  // ---- store: lane holds out[oc=mt*16+4g4+r][token=q0+c16] ----
  {
    const bool store_ok = (wv < 3) || (c16 == 15);  // tile 3 only stores token 48
    float* orow = outg + (size_t)win * (NTOK * CDIM) + q * 96;
#pragma unroll
    for (int mt = 0; mt < 6; ++mt) {
      int oc0 = mt * 16 + g4 * 4;
      if (store_ok) {
        float4 bb = *(const float4*)(bproj + oc0);
        float4 o4;
        o4.x = oacc[mt][0] + bb.x; o4.y = oacc[mt][1] + bb.y;
        o4.z = oacc[mt][2] + bb.z; o4.w = oacc[mt][3] + bb.w;
        *(float4*)(orow + oc0) = o4;
      }
    }
  }
}

extern "C" void kernel_launch(void* const* d_in, const int* in_sizes, int n_in,
                              void* d_out, int out_size, void* d_ws, size_t ws_size,
                              hipStream_t stream) {
  const float* x     = (const float*)d_in[0];
  const float* v     = (const float*)d_in[1];
  const float* wq    = (const float*)d_in[2];
  const float* bq    = (const float*)d_in[3];
  const float* wkv   = (const float*)d_in[4];
  const float* bkv   = (const float*)d_in[5];
  const float* wproj = (const float*)d_in[6];
  const float* bproj = (const float*)d_in[7];
  const float* rpb   = (const float*)d_in[8];
  const int*   relidx= (const int*)d_in[9];
  float* out = (float*)d_out;
  unsigned short* wsT = (unsigned short*)d_ws;
  float* biasf = (float*)((char*)d_ws + 73728);
  int nwin = in_sizes[0] / (NTOK * CDIM);   // 8192

  hipLaunchKernelGGL(prep, dim3(181), dim3(256), 0, stream,
                     wq, wkv, wproj, rpb, relidx, wsT, biasf);
  hipLaunchKernelGGL(attn_fused, dim3(nwin), dim3(256), 0, stream,
                     x, v, bq, bkv, bproj, wsT, biasf, out);
}